// Round 9
// baseline (542.593 us; speedup 1.0000x reference)
//
#include <hip/hip_runtime.h>
#include <hip/hip_fp16.h>

#define NB 256      // batch
#define NT 1024     // time
#define ND 64       // input dim
#define NH 128      // hidden dim

typedef __fp16 half8 __attribute__((ext_vector_type(8)));
typedef __fp16 half4v __attribute__((ext_vector_type(4)));
typedef float float4v __attribute__((ext_vector_type(4)));

#define LOG2E 1.44269504f
#define TWO_LOG2E 2.88539008f

static __device__ __forceinline__ float exp2_fast(float x) {
#if __has_builtin(__builtin_amdgcn_exp2f)
    return __builtin_amdgcn_exp2f(x);
#else
    return __expf(x * 0.69314718f);
#endif
}

// tanh(v) = 1 - 2/(exp2(2*log2e*v)+1)
static __device__ __forceinline__ float ftanh(float v) {
    float t = __builtin_amdgcn_rcpf(exp2_fast(v * TWO_LOG2E) + 1.0f);
    return __builtin_fmaf(-2.0f, t, 1.0f);
}

// lgkm-only barrier: does NOT drain vmcnt (stores / x prefetch keep flying)
static __device__ __forceinline__ void fast_barrier() {
    asm volatile("s_waitcnt lgkmcnt(0)\n\ts_barrier" ::: "memory");
}

// 8 waves (2/SIMD), block = batch. Wave w owns hidden units j in [16w, 16w+16):
// lane l16 holds ONE j (kg duplicates 4x -> minimal per-lane serial tail).
// Matvec y = W_hK·h = 4 INDEPENDENT MFMAs (K-split, 3-add tree) — one less
// dependent-MFMA link than v8. Chunk-boundary work (proj MFMAs, epilogues,
// x prefetch) is SPREAD into steps s=1/3/5/7/9 (wave-uniform, symmetric) so it
// hides under per-step LDS/MFMA latency instead of serializing between chunks.
// Tail runs on native exp2 with per-chunk premultiplied gates
// gl[s] = -(gxK+bxK+bhK)*log2e hoisted to f32 regs (off the serial chain).
// Only sync: one lgkm barrier per step for the h exchange.
__global__ __launch_bounds__(512, 2) void fused_rnn_v9(
        const float* __restrict__ x,
        const float* __restrict__ WxK, const float* __restrict__ bxK,
        const float* __restrict__ Wxz, const float* __restrict__ bxz,
        const float* __restrict__ Whk, const float* __restrict__ bhk,
        float* __restrict__ out) {
    __shared__ __align__(16) __fp16 hbuf[2][128];    // h fp16, dbuf per step parity
    __shared__ __align__(16) __fp16 gT[2][128][24];  // (gxK+bxK+bhK)^T: [j][s], 48B rows
    __shared__ __align__(16) __fp16 zT[2][128][24];  // tanh(gxz+bxz)^T: [j][s]

    const int tid = threadIdx.x;
    const int b = blockIdx.x;
    const int w = tid >> 6, lane = tid & 63;
    const int l16 = lane & 15, kg = lane >> 4;
    const int j = w * 16 + l16;              // this lane's single hidden unit

    // ---- W_hK^T B-fragments (4 MFMAs): B[k=kt*32+kg*8+e][n=l16] = Whk[j][k] ----
    half8 whT[4];
    #pragma unroll
    for (int kt = 0; kt < 4; ++kt) {
        const float* p = Whk + (size_t)j * NH + kt * 32 + kg * 8;
        float4v u = *(const float4v*)p, v = *(const float4v*)(p + 4);
        whT[kt] = (half8){(__fp16)u.x, (__fp16)u.y, (__fp16)u.z, (__fp16)u.w,
                          (__fp16)v.x, (__fp16)v.y, (__fp16)v.z, (__fp16)v.w};
    }

    // ---- proj B-fragments: rows 16w..16w+16 of WxK / Wxz ----
    half8 wxT[2][2];   // [mat][kt]
    #pragma unroll
    for (int mat = 0; mat < 2; ++mat) {
        const float* W = mat ? Wxz : WxK;
        #pragma unroll
        for (int kt = 0; kt < 2; ++kt) {
            const float* p = W + (size_t)j * ND + kt * 32 + kg * 8;
            float4v u = *(const float4v*)p, v = *(const float4v*)(p + 4);
            wxT[mat][kt] = (half8){(__fp16)u.x, (__fp16)u.y, (__fp16)u.z, (__fp16)u.w,
                                   (__fp16)v.x, (__fp16)v.y, (__fp16)v.z, (__fp16)v.w};
        }
    }
    const float bGK = bxK[j] + bhk[j];       // fold bhK into the staged gate
    const float bZ  = bxz[j];
    const float4v zero4 = {0.f, 0.f, 0.f, 0.f};

    const float* xb = x + (size_t)b * NT * ND;
    float4v xf[4];    // prefetched x chunk A-fragments (f32)

    // load x chunk c: A[row=l16 (timestep)][k=kt*32+kg*8+e]
    auto xload = [&](int c) {
        const float* px = xb + (size_t)c * 16 * 64 + (size_t)l16 * 64;
        #pragma unroll
        for (int kt = 0; kt < 2; ++kt) {
            const float* qp = px + kt * 32 + kg * 8;
            xf[2 * kt]     = *(const float4v*)qp;
            xf[2 * kt + 1] = *(const float4v*)(qp + 4);
        }
    };

    // full projection (prologue only; in-loop the same work is spread over steps)
    auto proj = [&](int dst) {
        half8 ax[2];
        #pragma unroll
        for (int kt = 0; kt < 2; ++kt) {
            float4v u = xf[2 * kt], v = xf[2 * kt + 1];
            ax[kt] = (half8){(__fp16)u.x, (__fp16)u.y, (__fp16)u.z, (__fp16)u.w,
                             (__fp16)v.x, (__fp16)v.y, (__fp16)v.z, (__fp16)v.w};
        }
        float4v pg = __builtin_amdgcn_mfma_f32_16x16x32_f16(ax[0], wxT[0][0], zero4, 0, 0, 0);
        pg = __builtin_amdgcn_mfma_f32_16x16x32_f16(ax[1], wxT[0][1], pg, 0, 0, 0);
        half4v hg = {(__fp16)(pg[0] + bGK), (__fp16)(pg[1] + bGK),
                     (__fp16)(pg[2] + bGK), (__fp16)(pg[3] + bGK)};
        *(half4v*)&gT[dst][j][kg * 4] = hg;
        float4v pz = __builtin_amdgcn_mfma_f32_16x16x32_f16(ax[0], wxT[1][0], zero4, 0, 0, 0);
        pz = __builtin_amdgcn_mfma_f32_16x16x32_f16(ax[1], wxT[1][1], pz, 0, 0, 0);
        half4v hz = {(__fp16)ftanh(pz[0] + bZ), (__fp16)ftanh(pz[1] + bZ),
                     (__fp16)ftanh(pz[2] + bZ), (__fp16)ftanh(pz[3] + bZ)};
        *(half4v*)&zT[dst][j][kg * 4] = hz;
    };

    // ---- prologue ----
    xload(0);
    if (tid < 128) hbuf[0][tid] = (__fp16)0.0f;   // h0 = 0
    proj(0);                                      // chunk 0 -> buf 0 (own rows)
    xload(1);
    __syncthreads();                              // hbuf + staged chunk visible

    float hn = 0.0f;
    float oreg[16];
    const size_t CPY = (size_t)NB * NT * NH;
    // kg==0 lanes store copy 0; kg==1 lanes store copy 1; kg>=2 store nothing
    float* obase = out + (size_t)b * NT * NH + (kg == 1 ? CPY : 0);

    for (int c = 0; c < 64; ++c) {
        const int cb = c & 1;

        // hoist this chunk's g/z: 4x ds_read_b128 then premultiplied f32 regs
        half8 gA = *(const half8*)&gT[cb][j][0];
        half8 gB = *(const half8*)&gT[cb][j][8];
        half8 zA = *(const half8*)&zT[cb][j][0];
        half8 zB = *(const half8*)&zT[cb][j][8];
        float glf[16], zvf[16];
        #pragma unroll
        for (int i = 0; i < 8; ++i) {
            glf[i]     = -(float)gA[i] * LOG2E;
            glf[i + 8] = -(float)gB[i] * LOG2E;
            zvf[i]     = (float)zA[i];
            zvf[i + 8] = (float)zB[i];
        }

        // spread-proj state (filled at s=1, consumed through s=7)
        half8 ax0, ax1;
        float4v pg, pz;

        #pragma unroll
        for (int s = 0; s < 16; ++s) {
            const int p = s & 1;
            // h A-fragments: broadcast reads (addr depends only on kg) — 4x b128
            half8 ah0 = *(const half8*)&hbuf[p][0 * 32 + kg * 8];
            half8 ah1 = *(const half8*)&hbuf[p][1 * 32 + kg * 8];
            half8 ah2 = *(const half8*)&hbuf[p][2 * 32 + kg * 8];
            half8 ah3 = *(const half8*)&hbuf[p][3 * 32 + kg * 8];

            const float d = zvf[s] - hn;      // off-chain vs the dot

            // y = W_hK·h : 4 INDEPENDENT MFMAs + 3-add tree; D col=l16 -> own j
            float4v aA = __builtin_amdgcn_mfma_f32_16x16x32_f16(ah0, whT[0], zero4, 0, 0, 0);
            float4v aB = __builtin_amdgcn_mfma_f32_16x16x32_f16(ah1, whT[1], zero4, 0, 0, 0);
            float4v aC = __builtin_amdgcn_mfma_f32_16x16x32_f16(ah2, whT[2], zero4, 0, 0, 0);
            float4v aD = __builtin_amdgcn_mfma_f32_16x16x32_f16(ah3, whT[3], zero4, 0, 0, 0);
            const float y = (aA[0] + aB[0]) + (aC[0] + aD[0]);

            // K = sigmoid(y + g) via exp2 (gl = -g*log2e premultiplied)
            const float K = __builtin_amdgcn_rcpf(
                1.0f + exp2_fast(__builtin_fmaf(y, -LOG2E, glf[s])));
            hn = ftanh(__builtin_fmaf(K, d, hn));
            oreg[s] = hn;

            if (kg == 0) hbuf[p ^ 1][j] = (__fp16)hn;   // publish own j

            // ---- spread chunk-boundary work (wave-uniform, symmetric) ----
            if (s == 1 && c < 63) {           // pack next x chunk, g-MFMAs
                float4v u0 = xf[0], v0 = xf[1], u1 = xf[2], v1 = xf[3];
                ax0 = (half8){(__fp16)u0.x, (__fp16)u0.y, (__fp16)u0.z, (__fp16)u0.w,
                              (__fp16)v0.x, (__fp16)v0.y, (__fp16)v0.z, (__fp16)v0.w};
                ax1 = (half8){(__fp16)u1.x, (__fp16)u1.y, (__fp16)u1.z, (__fp16)u1.w,
                              (__fp16)v1.x, (__fp16)v1.y, (__fp16)v1.z, (__fp16)v1.w};
                pg = __builtin_amdgcn_mfma_f32_16x16x32_f16(ax0, wxT[0][0], zero4, 0, 0, 0);
                pg = __builtin_amdgcn_mfma_f32_16x16x32_f16(ax1, wxT[0][1], pg, 0, 0, 0);
            }
            if (s == 3 && c < 63) {           // z-MFMAs
                pz = __builtin_amdgcn_mfma_f32_16x16x32_f16(ax0, wxT[1][0], zero4, 0, 0, 0);
                pz = __builtin_amdgcn_mfma_f32_16x16x32_f16(ax1, wxT[1][1], pz, 0, 0, 0);
            }
            if (s == 5 && c < 63) {           // g epilogue -> gT[next]
                half4v hg = {(__fp16)(pg[0] + bGK), (__fp16)(pg[1] + bGK),
                             (__fp16)(pg[2] + bGK), (__fp16)(pg[3] + bGK)};
                *(half4v*)&gT[cb ^ 1][j][kg * 4] = hg;
            }
            if (s == 7 && c < 63) {           // z epilogue -> zT[next]
                half4v hz = {(__fp16)ftanh(pz[0] + bZ), (__fp16)ftanh(pz[1] + bZ),
                             (__fp16)ftanh(pz[2] + bZ), (__fp16)ftanh(pz[3] + bZ)};
                *(half4v*)&zT[cb ^ 1][j][kg * 4] = hz;
            }
            if (s == 9 && c < 62) xload(c + 2);   // prefetch x two chunks ahead

            fast_barrier();                   // the ONLY sync: h exchange
        }

        // burst-flush outputs (both copies) off the step chain; fire-and-forget
        if (kg < 2) {
            float* po = obase + (size_t)(c * 16) * NH;
            #pragma unroll
            for (int s = 0; s < 16; ++s) {
                po[j] = oreg[s];
                po += NH;
            }
        }
    }
}

extern "C" void kernel_launch(void* const* d_in, const int* in_sizes, int n_in,
                              void* d_out, int out_size, void* d_ws, size_t ws_size,
                              hipStream_t stream) {
    (void)in_sizes; (void)n_in; (void)d_ws; (void)ws_size; (void)out_size;
    const float* x   = (const float*)d_in[0];
    const float* WxK = (const float*)d_in[1];
    const float* bxK = (const float*)d_in[2];
    const float* Wxz = (const float*)d_in[3];
    const float* bxz = (const float*)d_in[4];
    const float* Whk = (const float*)d_in[5];
    const float* bhk = (const float*)d_in[6];
    float* out = (float*)d_out;

    fused_rnn_v9<<<256, 512, 0, stream>>>(x, WxK, bxK, Wxz, bxz, Whk, bhk, out);
}